// Round 6
// baseline (177.328 us; speedup 1.0000x reference)
//
#include <hip/hip_runtime.h>
#include <math.h>
#include <stdint.h>

// Transformer forward. R18 == R17 resubmitted (R17 hit an infra failure:
// "MI355X container failed twice" -- no compile/bench signal; kernel
// re-audited for hang/OOB: none). Changes vs R16 (passed 176.5us; flash 67.6):
//  - flash: KVBLK 64 -> 128. Each iter stages K[128x64] + V^T[64x128] (64KB
//    LDS dbuf, still exactly 2 blocks/CU) and computes two 64-key halves with
//    NO barrier between them: barrier pairs 64 -> 32, and two independent
//    QK->exp2->PV chains sit in one barrier region so MFMA/VALU/LDS overlap
//    across halves (R16 counters: MfmaUtil 48 / VALU 43 / LDS ~40 -- jointly
//    bound by phase-lock, not capacity). o/o1 accumulation order bit-identical
//    (two halves == two old iters). vmcnt 2 -> 4 (4 DMA/thread/iter).
//  - flash: s_setprio(1/0) around PV MFMA clusters (T5, attn +4-7%).
//  - All R16 numerics pinned: in-register P via compiler (__bf16) casts,
//    psi-permuted V, XCD relabel, split-K=2, 32 q/wave, zero4 C-in.
//  - prep, gemm_qkv, gemm_out unchanged (passing).

typedef unsigned short u16;
typedef __attribute__((ext_vector_type(8))) __bf16 bf16x8;
typedef __attribute__((ext_vector_type(4))) __bf16 bf16x4;
typedef __attribute__((ext_vector_type(4))) float f32x4;

#define AS1 __attribute__((address_space(1)))
#define AS3 __attribute__((address_space(3)))

__device__ __forceinline__ void async16(const void* g, void* l) {
  __builtin_amdgcn_global_load_lds((const AS1 void*)g, (AS3 void*)l, 16, 0, 0);
}

__device__ __forceinline__ u16 f2bf(float f) {  // RNE fp32->bf16
  union { float f; unsigned u; } c; c.f = f;
  return (u16)((c.u + 0x7fffu + ((c.u >> 16) & 1u)) >> 16);
}

// ---------------- prep (one launch, block-range dispatch) ----------------
// [0,96):     wf GEMM  wfT[1536][256] = (Wp@Wqkv)^T, fp32 staged inline
// [96,120):   bias_fuse bfused[n] = bp@Wqkv[:,n] + bqkv[n]
// [120,632):  Wo [512][256] -> woT [256][512]
// [632,2680): prompt fp32 -> bf16 (524288 float4)
__global__ void prep_kernel(const float* __restrict__ prompt, u16* __restrict__ pbf,
                            const float* __restrict__ Wp, const float* __restrict__ Wqkv,
                            const float* __restrict__ Wo, u16* __restrict__ woT,
                            const float* __restrict__ bp, const float* __restrict__ bqkv,
                            float* __restrict__ bfused, u16* __restrict__ wfT) {
  __shared__ u16 Asf[64 * 40];
  __shared__ u16 Bsf[64 * 32];
  __shared__ float red[256];
  const int bid = blockIdx.x, tid = threadIdx.x;
  if (bid < 96) {                // wf GEMM: 4 k-tiles x 24 n-tiles of 64x64
    const int k0 = (bid & 3) * 64, n0 = (bid >> 2) * 64;
    const int lane = tid & 63, w = tid >> 6;
    const int wr = w >> 1, wc = w & 1;
    const int lr = lane >> 4, lc = lane & 15;
    f32x4 acc[2][2];
#pragma unroll
    for (int a = 0; a < 2; a++)
#pragma unroll
      for (int b = 0; b < 2; b++) acc[a][b] = (f32x4){0.f, 0.f, 0.f, 0.f};
    for (int e0 = 0; e0 < 512; e0 += 32) {
      {  // As[n][e] = bf16(Wqkv[e0+e][n0+n])
        const int er = tid >> 3, ng = (tid & 7) * 8;
        float4 v1 = *(const float4*)&Wqkv[(e0 + er) * 1536 + n0 + ng];
        float4 v2 = *(const float4*)&Wqkv[(e0 + er) * 1536 + n0 + ng + 4];
        Asf[(ng + 0) * 40 + er] = f2bf(v1.x); Asf[(ng + 1) * 40 + er] = f2bf(v1.y);
        Asf[(ng + 2) * 40 + er] = f2bf(v1.z); Asf[(ng + 3) * 40 + er] = f2bf(v1.w);
        Asf[(ng + 4) * 40 + er] = f2bf(v2.x); Asf[(ng + 5) * 40 + er] = f2bf(v2.y);
        Asf[(ng + 6) * 40 + er] = f2bf(v2.z); Asf[(ng + 7) * 40 + er] = f2bf(v2.w);
      }
      {  // Bs[k][e] = bf16(Wp[k0+k][e0+e])
        const int kr = tid >> 2, ec = (tid & 3) * 8;
        float4 w1 = *(const float4*)&Wp[(k0 + kr) * 512 + e0 + ec];
        float4 w2 = *(const float4*)&Wp[(k0 + kr) * 512 + e0 + ec + 4];
        u16 tmp[8] = {f2bf(w1.x), f2bf(w1.y), f2bf(w1.z), f2bf(w1.w),
                      f2bf(w2.x), f2bf(w2.y), f2bf(w2.z), f2bf(w2.w)};
        *(uint4*)&Bsf[kr * 32 + ec] = *(const uint4*)&tmp[0];
      }
      __syncthreads();
      bf16x8 af[2], bf2[2];
#pragma unroll
      for (int mi = 0; mi < 2; mi++)
        af[mi] = *(const bf16x8*)&Asf[(wr * 32 + mi * 16 + lc) * 40 + lr * 8];
#pragma unroll
      for (int nj = 0; nj < 2; nj++)
        bf2[nj] = *(const bf16x8*)&Bsf[(wc * 32 + nj * 16 + lc) * 32 + lr * 8];
#pragma unroll
      for (int mi = 0; mi < 2; mi++)
#pragma unroll
        for (int nj = 0; nj < 2; nj++)
          acc[mi][nj] = __builtin_amdgcn_mfma_f32_16x16x32_bf16(af[mi], bf2[nj], acc[mi][nj], 0, 0, 0);
      __syncthreads();
    }
#pragma unroll
    for (int mi = 0; mi < 2; mi++)
#pragma unroll
      for (int nj = 0; nj < 2; nj++)
#pragma unroll
        for (int r = 0; r < 4; r++)
          wfT[(n0 + wr * 32 + mi * 16 + 4 * lr + r) * 256 + k0 + wc * 32 + nj * 16 + lc] =
              f2bf(acc[mi][nj][r]);
  } else if (bid < 120) {        // bias fuse
    const int nloc = tid & 63, slice = tid >> 6;
    const int n = (bid - 96) * 64 + nloc;
    float s = 0.f;
#pragma unroll 8
    for (int e = slice * 128; e < slice * 128 + 128; e++) s += bp[e] * Wqkv[e * 1536 + n];
    red[tid] = s;
    __syncthreads();
    if (slice == 0)
      bfused[n] = red[nloc] + red[64 + nloc] + red[128 + nloc] + red[192 + nloc] + bqkv[n];
  } else if (bid < 632) {        // Wo^T
    int j = (bid - 120) * 256 + tid;
    int n = j >> 9, k = j & 511;
    woT[j] = f2bf(Wo[k * 256 + n]);
  } else {                       // prompt cvt
    int i = (bid - 632) * 256 + tid;
    float4 v = ((const float4*)prompt)[i];
    ushort4 o;
    o.x = f2bf(v.x); o.y = f2bf(v.y); o.z = f2bf(v.z); o.w = f2bf(v.w);
    ((ushort4*)pbf)[i] = o;
  }
}

// ---------------- qkv GEMM (V-write psi-permuted along t) ----------------
__global__ __launch_bounds__(256) void gemm_qkv(
    const u16* __restrict__ A, const u16* __restrict__ Bt, const float* __restrict__ bias,
    u16* __restrict__ qO, u16* __restrict__ kO, u16* __restrict__ vO, int K) {
  constexpr int TM = 128, MI = 4, NJ = 4;
  __shared__ __align__(16) u16 As[2][TM * 32];
  __shared__ __align__(16) u16 Bs[2][TM * 32];
  const int tid = threadIdx.x;
  const int lane = tid & 63, w = tid >> 6;
  const int wr = w >> 1, wc = w & 1;
  const int lr = lane >> 4, lc = lane & 15;
  const long tileM = (long)blockIdx.y * 128;
  const long tileN = (long)blockIdx.x * 128;

  f32x4 acc[MI][NJ];
#pragma unroll
  for (int a = 0; a < MI; a++)
#pragma unroll
    for (int b = 0; b < NJ; b++) acc[a][b] = (f32x4){0.f, 0.f, 0.f, 0.f};

  const int r0 = lane >> 2;
  const int blk = lane & 3;

  auto stage = [&](int buf, int k0) {
#pragma unroll
    for (int i = 0; i < 2; i++) {
      int r = w * 32 + i * 16 + r0;
      int g = (blk ^ ((r >> 1) & 3)) << 3;
      async16(A + (tileM + r) * (long)K + k0 + g, (void*)&As[buf][(w * 32 + i * 16) * 32]);
      async16(Bt + (tileN + r) * (long)K + k0 + g, (void*)&Bs[buf][(w * 32 + i * 16) * 32]);
    }
  };

  stage(0, 0);
  for (int k0 = 0; k0 < K; k0 += 32) {
    const int cur = (k0 >> 5) & 1;
    stage(cur ^ 1, (k0 + 32 < K) ? k0 + 32 : 0);
    asm volatile("s_waitcnt vmcnt(4)" ::: "memory");
    asm volatile("s_barrier" ::: "memory");

    bf16x8 af[MI], bfv[NJ];
#pragma unroll
    for (int mi = 0; mi < MI; mi++) {
      int r = wr * 64 + mi * 16 + lc;
      af[mi] = *(const bf16x8*)&As[cur][r * 32 + ((lr ^ ((r >> 1) & 3)) << 3)];
    }
#pragma unroll
    for (int nj = 0; nj < NJ; nj++) {
      int r = wc * 64 + nj * 16 + lc;
      bfv[nj] = *(const bf16x8*)&Bs[cur][r * 32 + ((lr ^ ((r >> 1) & 3)) << 3)];
    }
#pragma unroll
    for (int mi = 0; mi < MI; mi++)
#pragma unroll
      for (int nj = 0; nj < NJ; nj++)
        acc[mi][nj] = __builtin_amdgcn_mfma_f32_16x16x32_bf16(af[mi], bfv[nj], acc[mi][nj], 0, 0, 0);
    asm volatile("s_barrier" ::: "memory");
  }

#pragma unroll
  for (int mi = 0; mi < MI; mi++)
#pragma unroll
    for (int nj = 0; nj < NJ; nj++) {
      long col = tileN + wc * 64 + nj * 16 + lc;
      float bcol = bias[col];
      long row0 = tileM + wr * 64 + mi * 16 + lr * 4;
      int sec = (int)(col >> 9);
      int c2 = (int)(col & 511);
      int h = c2 >> 6, d = c2 & 63;
      long pl = (row0 >> 12) * 8 + h;
      long t0 = row0 & 4095;
      if (sec == 2) {
        ushort4 pk;
        pk.x = f2bf(acc[mi][nj][0] + bcol);
        pk.y = f2bf(acc[mi][nj][1] + bcol);
        pk.z = f2bf(acc[mi][nj][2] + bcol);
        pk.w = f2bf(acc[mi][nj][3] + bcol);
        // psi: within each 32-key chunk, key-group g -> position-group
        // posg = ((g&3)<<1)|(g>>2); pos 8b+j holds key 4b+(j&3)+16*(j>>2),
        // matching flash's in-register P fragment (R12-pinned C-layout).
        int g = (int)((t0 >> 2) & 7);
        int posg = ((g & 3) << 1) | (g >> 2);
        long tp = (t0 & ~31L) | (posg << 2);
        *(ushort4*)&vO[(pl * 64 + d) * 4096 + tp] = pk;
      } else {
        u16* dst = sec ? kO : qO;
        const float sc = sec ? 1.f : 0.18033688f;  // q: 1/8 * log2(e)
#pragma unroll
        for (int r = 0; r < 4; r++)
          dst[((pl * 4096 + t0 + r) << 6) + d] = f2bf((acc[mi][nj][r] + bcol) * sc);
      }
    }
}

// ---------------- flash attention (split-K=2, in-register P, KVBLK=128) ----------------
// Q,K bf16 [b*h,4096,64] (q pre-scaled by 0.125*log2e); VT bf16 [b*h,64,4096]
// psi-permuted along t within 32-key chunks.
// 8 waves x 32 q = 256 q/block; grid (16,16,2) = 512 blocks = 2/CU.
// LDS: K[128][64] + V^T[64][128] dbuf = 64KB -> 2 blocks/CU, 128KB/CU.
// Per iter: stage next 128-key tile, then TWO 64-key halves with no barrier
// between them (independent QK->exp2->PV chains overlap). o/o1 accumulation
// order identical to R16 (two halves == two old iters).
__global__ __launch_bounds__(512, 4) void flash_attn(
    const u16* __restrict__ Q, const u16* __restrict__ Kg,
    const u16* __restrict__ VTg, u16* __restrict__ Op, float* __restrict__ lp) {
  __shared__ __align__(16) u16 KV[2][16384];   // per buf: Ks[128*64] | Vt[64*128]

  const int tid = threadIdx.x, lane = tid & 63, w = tid >> 6;  // w in 0..7
  // block-id relabel: all 16 qtiles of one (plane,split) -> same XCD (g%8)
  const int linear = blockIdx.x + 16 * (blockIdx.y + 16 * blockIdx.z);
  const int qt = linear >> 5;                  // qtile 0..15
  const int g = linear & 31;
  const int plane = g & 15;                    // b*8+h
  const int split = g >> 4;                    // 0/1: keys [0,2048) / [2048,4096)
  const int lr = lane >> 4, lc = lane & 15;
  const long pbase = (long)plane << 18;        // *4096*64
  const int qr0 = qt * 256 + w * 32;
  const int kb0 = split * 2048;                // first key of this split

  bf16x8 bq[2][2];
#pragma unroll
  for (int qi = 0; qi < 2; qi++)
#pragma unroll
    for (int kk = 0; kk < 2; kk++)
      bq[qi][kk] = *(const bf16x8*)&Q[pbase + (long)(qr0 + qi * 16 + lc) * 64 + kk * 32 + lr * 8];

  bf16x8 ones;
#pragma unroll
  for (int u = 0; u < 8; u++) ones[u] = (__bf16)1.0f;
  const f32x4 zero4 = (f32x4){0.f, 0.f, 0.f, 0.f};

  f32x4 o[2][4], o1[2];
#pragma unroll
  for (int mi = 0; mi < 2; mi++) {
    o1[mi] = zero4;
#pragma unroll
    for (int nj = 0; nj < 4; nj++) o[mi][nj] = zero4;
  }

  const int krow = lane >> 3, kblk = lane & 7;   // K-stage: 8 rows x 8 chunks
  const int vrow = lane >> 4, vchk = lane & 15;  // V-stage: 4 rows x 16 chunks

  auto stage = [&](int buf, int kb) {
    const u16* kS = Kg + pbase + (long)kb * 64;
    const u16* vS = VTg + pbase + kb;
    u16* Kb = &KV[buf][0];
    u16* Vb = &KV[buf][8192];
#pragma unroll
    for (int i = 0; i < 2; i++) {              // K: rows w*16+i*8 .. +7
      int r = w * 16 + i * 8 + krow;
      async16(kS + (long)r * 64 + ((kblk ^ (r & 7)) << 3),
              (void*)&Kb[(w * 16 + i * 8) * 64]);
    }
#pragma unroll
    for (int i = 0; i < 2; i++) {              // V: d-rows w*8+i*4 .. +3, 16 chunks
      int r = w * 8 + i * 4 + vrow;
      int c = vchk ^ (r & 7);                  // LDS chunk vchk holds global chunk c
      async16(vS + (long)r * 4096 + (c << 3),
              (void*)&Vb[(w * 8 + i * 4) * 128]);
    }
  };

  stage(0, kb0);
  for (int jj = 0; jj < 16; jj++) {
    const int cur = jj & 1;
    stage(cur ^ 1, (jj + 1 < 16) ? kb0 + (jj + 1) * 128 : kb0);  // jj=15: dummy
    asm volatile("s_waitcnt vmcnt(4)" ::: "memory");
    asm volatile("s_barrier" ::: "memory");

    const u16* Ks = &KV[cur][0];
    const u16* Vt = &KV[cur][8192];

#pragma unroll
    for (int half = 0; half < 2; half++) {
      // S^T tile: [64 key][32 q] per wave, keys half*64..+63
      f32x4 s[4][2];
#pragma unroll
      for (int ki = 0; ki < 4; ki++) {
        const int row = half * 64 + ki * 16 + lc;
        bf16x8 ak[2];
#pragma unroll
        for (int kk = 0; kk < 2; kk++)
          ak[kk] = *(const bf16x8*)&Ks[row * 64 + (((kk * 4 + lr) ^ (row & 7)) << 3)];
#pragma unroll
        for (int qi = 0; qi < 2; qi++) {
          s[ki][qi] = __builtin_amdgcn_mfma_f32_16x16x32_bf16(ak[0], bq[qi][0], zero4, 0, 0, 0);
          s[ki][qi] = __builtin_amdgcn_mfma_f32_16x16x32_bf16(ak[1], bq[qi][1], s[ki][qi], 0, 0, 0);
        }
      }

      // p = exp2(s) -> bf16 (compiler casts); A-frag IS the C-layout
      // (V is psi-permuted), zero cross-lane ops, no LDS.
#pragma unroll
      for (int kk = 0; kk < 2; kk++) {
        bf16x8 ap[2];
#pragma unroll
        for (int qi = 0; qi < 2; qi++) {
          bf16x8 p;
#pragma unroll
          for (int r = 0; r < 4; r++) {
            p[r]     = (__bf16)__builtin_amdgcn_exp2f(s[2 * kk][qi][r]);
            p[4 + r] = (__bf16)__builtin_amdgcn_exp2f(s[2 * kk + 1][qi][r]);
          }
          ap[qi] = p;
        }
        __builtin_amdgcn_s_setprio(1);
#pragma unroll
        for (int nj = 0; nj < 4; nj++) {
          const int row = nj * 16 + lc;
          bf16x8 bv = *(const bf16x8*)&Vt[row * 128 + (((half * 8 + kk * 4 + lr) ^ (row & 7)) << 3)];
#pragma unroll
          for (int mi = 0; mi < 2; mi++)
            o[mi][nj] = __builtin_amdgcn_mfma_f32_16x16x32_bf16(ap[mi], bv, o[mi][nj], 0, 0, 0);
        }
#pragma unroll
        for (int mi = 0; mi < 2; mi++)
          o1[mi] = __builtin_amdgcn_mfma_f32_16x16x32_bf16(ap[mi], ones, o1[mi], 0, 0, 0);
        __builtin_amdgcn_s_setprio(0);
      }
    }
    asm volatile("s_barrier" ::: "memory");
  }

  // epilogue: bf16 O-partial (undivided) + fp32 l-partial
  const int bb = plane >> 3, h = plane & 7;
  u16* Ob = Op + (long)split * 4194304;        // 8 MiB per split
#pragma unroll
  for (int mi = 0; mi < 2; mi++)
#pragma unroll
    for (int r = 0; r < 4; r++) {
      long t = qr0 + mi * 16 + 4 * lr + r;
#pragma unroll
      for (int nj = 0; nj < 4; nj++)
        Ob[(((long)(bb * 4096 + t) * 8 + h) << 6) + nj * 16 + lc] = f2bf(o[mi][nj][r]);
      if (lc == 0) lp[((split * 16 + plane) << 12) + t] = o1[mi][r];
    }
}

// ---------------- out GEMM (+fused split-K merge): out = ((O0+O1)/l) @ woT^T + bo ----------------
// A staged through VGPRs: (O0+O1)*inv(l0+l1) -> bf16 -> LDS. B via async16 DMA.
__global__ __launch_bounds__(256) void gemm_out(
    const u16* __restrict__ Op, const float* __restrict__ lp,
    const u16* __restrict__ Bt, const float* __restrict__ bias,
    float* __restrict__ outf) {
  constexpr int K = 512;
  __shared__ __align__(16) u16 As[2][64 * 32];
  __shared__ __align__(16) u16 Bs[2][64 * 32];
  const int tid = threadIdx.x;
  const int lane = tid & 63, w = tid >> 6;
  const int wr = w >> 1, wc = w & 1;
  const int lr = lane >> 4, lc = lane & 15;
  const long tileM = (long)blockIdx.y * 64;
  const long tileN = (long)blockIdx.x * 64;

  f32x4 acc[2][2];
#pragma unroll
  for (int a = 0; a < 2; a++)
#pragma unroll
    for (int b = 0; b < 2; b++) acc[a][b] = (f32x4){0.f, 0.f, 0.f, 0.f};

  const int r0 = lane >> 2;
  const int blk = lane & 3;

  auto stageB = [&](int buf, int k0) {
    int r = w * 16 + r0;
    int g = (blk ^ ((r >> 1) & 3)) << 3;
    async16(Bt + (tileN + r) * (long)K + k0 + g, (void*)&Bs[buf][(w * 16) * 32]);
  };

  // A merge-staging geometry: thread covers row ar, 16B block ablk
  const int ar = tid >> 2, ablk = tid & 3;
  const long arow = tileM + ar;
  const int ab = (int)(arow >> 12), at = (int)(arow & 4095);

  auto stageA = [&](int buf, int k0) {
    int h = k0 >> 6;
    float l = lp[(long)((ab * 8 + h) << 12) + at] +
              lp[(long)((16 + ab * 8 + h) << 12) + at];
    float inv = 1.f / l;
    long idx = arow * 512 + k0 + ablk * 8;
    bf16x8 v0 = *(const bf16x8*)&Op[idx];
    bf16x8 v1 = *(const bf16x8*)&Op[4194304 + idx];
    u16 tmp[8];
#pragma unroll
    for (int e = 0; e < 8; e++)
      tmp[e] = f2bf(((float)v0[e] + (float)v1[e]) * inv);
    *(uint4*)&As[buf][ar * 32 + ((ablk ^ ((ar >> 1) & 3)) << 3)] = *(const uint4*)&tmp[0];
  };

  stageB(0, 0);
  for (int k0 = 0; k0 < K; k0 += 32) {
    const int cur = (k0 >> 5) & 1;
    stageB(cur ^ 1, (k0 + 32 < K) ? k0 + 32 : 0);
    stageA(cur, k0);
    // drain A ds_writes + this tile's B DMA; leave next-B (1 inst) in flight
    asm volatile("s_waitcnt vmcnt(1) lgkmcnt(0)" ::: "memory");
    asm volatile("s_barrier" ::: "memory");

    bf16x8 af[2], bfv[2];
#pragma unroll
    for (int mi = 0; mi < 2; mi++) {
      int r = wr * 32 + mi * 16 + lc;
      af[mi] = *(const bf16x8*)&As[cur][r * 32 + ((lr ^ ((r >> 1) & 3)) << 3)];
    }
#pragma unroll
    for (int nj = 0; nj < 2; nj++) {
      int r = wc * 32 + nj * 16 + lc;
      bfv[nj] = *(const bf16x8*)&Bs[cur][r * 32 + ((lr ^ ((r >> 1) & 3)) << 3)];
    }
#pragma unroll
    for (int mi = 0; mi < 2; mi++)
#pragma unroll
      for (int nj = 0; nj < 2; nj++)
        acc[mi][nj] = __builtin_amdgcn_mfma_f32_16x16x32_bf16(af[mi], bfv[nj], acc[mi][nj], 0, 0, 0);
    asm volatile("s_barrier" ::: "memory");
  }

#pragma unroll
  for (int mi = 0; mi < 2; mi++)
#pragma unroll
    for (int nj = 0; nj < 2; nj++) {
      long col = tileN + wc * 32 + nj * 16 + lc;
      float bcol = bias[col];
      long row0 = tileM + wr * 32 + mi * 16 + lr * 4;
#pragma unroll
      for (int r = 0; r < 4; r++)
        outf[(row0 + r) * 256 + col] = acc[mi][nj][r] + bcol;
    }
}

// ---------------- launch ----------------
extern "C" void kernel_launch(void* const* d_in, const int* in_sizes, int n_in,
                              void* d_out, int out_size, void* d_ws, size_t ws_size,
                              hipStream_t stream) {
  const float* prompt = (const float*)d_in[0];
  const float* Wp = (const float*)d_in[1];
  const float* bp = (const float*)d_in[2];
  const float* Wqkv = (const float*)d_in[3];
  const float* bqkv = (const float*)d_in[4];
  const float* Wo = (const float*)d_in[5];
  const float* bo = (const float*)d_in[6];
  float* out = (float*)d_out;

  char* ws = (char*)d_ws;
  const size_t MiB = 1024 * 1024;
  u16* qb     = (u16*)(ws + 0);           // [b,h,t,d]  8 MiB
  u16* kb     = (u16*)(ws + 8 * MiB);     // [b,h,t,d]  8 MiB
  u16* vb     = (u16*)(ws + 16 * MiB);    // [b,h,d,t(psi)]  8 MiB (transposed)
  u16* pbf    = (u16*)(ws + 24 * MiB);    // [8192,256] bf16 4 MiB (dead after qkv)
  float* lpp  = (float*)(ws + 24 * MiB);  // [2][16][4096] fp32 512 KiB (overlays pbf)
  u16* Op     = (u16*)(ws + 28 * MiB);    // [2][b,t,h*d] bf16 partials, 2x8 MiB
  u16* woT    = (u16*)(ws + 44 * MiB);                  // [256,512]  256 KiB
  u16* wfT    = (u16*)(ws + 44 * MiB + 256 * 1024);     // [1536,256] 768 KiB
  float* bfused = (float*)(ws + 45 * MiB);              // [1536] fp32

  prep_kernel<<<dim3(2680), dim3(256), 0, stream>>>(
      prompt, pbf, Wp, Wqkv, Wo, woT, bp, bqkv, bfused, wfT);

  // qkv = prompt @ Wfused + bfused -> q(scaled)/k [b,h,t,d], v^T [b,h,d,t(psi)]
  gemm_qkv<<<dim3(12, 64), dim3(256), 0, stream>>>(
      pbf, wfT, bfused, qb, kb, vb, 256);

  // flash attention: in-register P, 256 q/block, KVBLK=128, 512 blocks = 2/CU
  flash_attn<<<dim3(16, 16, 2), dim3(512), 0, stream>>>(qb, kb, vb, Op, lpp);

  // out = ((O0+O1)/(l0+l1)) @ Wo + bo  (merge fused into A-staging)
  gemm_out<<<dim3(4, 128), dim3(256), 0, stream>>>(Op, lpp, woT, bo, out);
}

// Round 7
// 175.964 us; speedup vs baseline: 1.0077x; 1.0077x over previous
//
#include <hip/hip_runtime.h>
#include <math.h>
#include <stdint.h>

// Transformer forward. R19 changes vs R18 (177.3us; flash 70.7):
//  - flash: REVERTED verbatim to R16 (67.6us, 0 conflicts). R18's KVBLK=128
//    bought no overlap (MfmaUtil unchanged) and re-added 4.19M bank conflicts.
//  - gemm_qkv: epilogue rewritten for coalesced stores. Old: V stored 8B/lane
//    at 8KB stride (~8x write amplification), q/k stored 64 scalar u16/thread
//    in 32B segments (~2x). New: stage C-tile to LDS ET[n][m+pad] (bf16x4
//    vector writes from acc, psi applied to m for the V section), then
//    V: bf16x8 row reads -> 256B-contiguous global stores;
//    q/k: scalar column gathers -> uint4 stores, 1KB contiguous per wave.
//    All conversions via integer-RNE f2bf -> output bit-identical.
//    LDS: single SH buffer 33792B (As/Bs dbuf 32KB reused as ET after drain).
//  - prep, gemm_out, launch unchanged (passing).

typedef unsigned short u16;
typedef __attribute__((ext_vector_type(8))) __bf16 bf16x8;
typedef __attribute__((ext_vector_type(4))) __bf16 bf16x4;
typedef __attribute__((ext_vector_type(4))) float f32x4;

#define AS1 __attribute__((address_space(1)))
#define AS3 __attribute__((address_space(3)))

__device__ __forceinline__ void async16(const void* g, void* l) {
  __builtin_amdgcn_global_load_lds((const AS1 void*)g, (AS3 void*)l, 16, 0, 0);
}

__device__ __forceinline__ u16 f2bf(float f) {  // RNE fp32->bf16
  union { float f; unsigned u; } c; c.f = f;
  return (u16)((c.u + 0x7fffu + ((c.u >> 16) & 1u)) >> 16);
}

// ---------------- prep (one launch, block-range dispatch) ----------------
// [0,96):     wf GEMM  wfT[1536][256] = (Wp@Wqkv)^T, fp32 staged inline
// [96,120):   bias_fuse bfused[n] = bp@Wqkv[:,n] + bqkv[n]
// [120,632):  Wo [512][256] -> woT [256][512]
// [632,2680): prompt fp32 -> bf16 (524288 float4)
__global__ void prep_kernel(const float* __restrict__ prompt, u16* __restrict__ pbf,
                            const float* __restrict__ Wp, const float* __restrict__ Wqkv,
                            const float* __restrict__ Wo, u16* __restrict__ woT,
                            const float* __restrict__ bp, const float* __restrict__ bqkv,
                            float* __restrict__ bfused, u16* __restrict__ wfT) {
  __shared__ u16 Asf[64 * 40];
  __shared__ u16 Bsf[64 * 32];
  __shared__ float red[256];
  const int bid = blockIdx.x, tid = threadIdx.x;
  if (bid < 96) {                // wf GEMM: 4 k-tiles x 24 n-tiles of 64x64
    const int k0 = (bid & 3) * 64, n0 = (bid >> 2) * 64;
    const int lane = tid & 63, w = tid >> 6;
    const int wr = w >> 1, wc = w & 1;
    const int lr = lane >> 4, lc = lane & 15;
    f32x4 acc[2][2];
#pragma unroll
    for (int a = 0; a < 2; a++)
#pragma unroll
      for (int b = 0; b < 2; b++) acc[a][b] = (f32x4){0.f, 0.f, 0.f, 0.f};
    for (int e0 = 0; e0 < 512; e0 += 32) {
      {  // As[n][e] = bf16(Wqkv[e0+e][n0+n])
        const int er = tid >> 3, ng = (tid & 7) * 8;
        float4 v1 = *(const float4*)&Wqkv[(e0 + er) * 1536 + n0 + ng];
        float4 v2 = *(const float4*)&Wqkv[(e0 + er) * 1536 + n0 + ng + 4];
        Asf[(ng + 0) * 40 + er] = f2bf(v1.x); Asf[(ng + 1) * 40 + er] = f2bf(v1.y);
        Asf[(ng + 2) * 40 + er] = f2bf(v1.z); Asf[(ng + 3) * 40 + er] = f2bf(v1.w);
        Asf[(ng + 4) * 40 + er] = f2bf(v2.x); Asf[(ng + 5) * 40 + er] = f2bf(v2.y);
        Asf[(ng + 6) * 40 + er] = f2bf(v2.z); Asf[(ng + 7) * 40 + er] = f2bf(v2.w);
      }
      {  // Bs[k][e] = bf16(Wp[k0+k][e0+e])
        const int kr = tid >> 2, ec = (tid & 3) * 8;
        float4 w1 = *(const float4*)&Wp[(k0 + kr) * 512 + e0 + ec];
        float4 w2 = *(const float4*)&Wp[(k0 + kr) * 512 + e0 + ec + 4];
        u16 tmp[8] = {f2bf(w1.x), f2bf(w1.y), f2bf(w1.z), f2bf(w1.w),
                      f2bf(w2.x), f2bf(w2.y), f2bf(w2.z), f2bf(w2.w)};
        *(uint4*)&Bsf[kr * 32 + ec] = *(const uint4*)&tmp[0];
      }
      __syncthreads();
      bf16x8 af[2], bf2[2];
#pragma unroll
      for (int mi = 0; mi < 2; mi++)
        af[mi] = *(const bf16x8*)&Asf[(wr * 32 + mi * 16 + lc) * 40 + lr * 8];
#pragma unroll
      for (int nj = 0; nj < 2; nj++)
        bf2[nj] = *(const bf16x8*)&Bsf[(wc * 32 + nj * 16 + lc) * 32 + lr * 8];
#pragma unroll
      for (int mi = 0; mi < 2; mi++)
#pragma unroll
        for (int nj = 0; nj < 2; nj++)
          acc[mi][nj] = __builtin_amdgcn_mfma_f32_16x16x32_bf16(af[mi], bf2[nj], acc[mi][nj], 0, 0, 0);
      __syncthreads();
    }
#pragma unroll
    for (int mi = 0; mi < 2; mi++)
#pragma unroll
      for (int nj = 0; nj < 2; nj++)
#pragma unroll
        for (int r = 0; r < 4; r++)
          wfT[(n0 + wr * 32 + mi * 16 + 4 * lr + r) * 256 + k0 + wc * 32 + nj * 16 + lc] =
              f2bf(acc[mi][nj][r]);
  } else if (bid < 120) {        // bias fuse
    const int nloc = tid & 63, slice = tid >> 6;
    const int n = (bid - 96) * 64 + nloc;
    float s = 0.f;
#pragma unroll 8
    for (int e = slice * 128; e < slice * 128 + 128; e++) s += bp[e] * Wqkv[e * 1536 + n];
    red[tid] = s;
    __syncthreads();
    if (slice == 0)
      bfused[n] = red[nloc] + red[64 + nloc] + red[128 + nloc] + red[192 + nloc] + bqkv[n];
  } else if (bid < 632) {        // Wo^T
    int j = (bid - 120) * 256 + tid;
    int n = j >> 9, k = j & 511;
    woT[j] = f2bf(Wo[k * 256 + n]);
  } else {                       // prompt cvt
    int i = (bid - 632) * 256 + tid;
    float4 v = ((const float4*)prompt)[i];
    ushort4 o;
    o.x = f2bf(v.x); o.y = f2bf(v.y); o.z = f2bf(v.z); o.w = f2bf(v.w);
    ((ushort4*)pbf)[i] = o;
  }
}

// ---------------- qkv GEMM (coalesced epilogue via LDS transpose) ----------------
// SH carve: K-loop: As dbuf = SH[0..8192), Bs dbuf = SH[8192..16384) (u16 idx).
// Epilogue: ET[128 n][132 m] (pad 4, 8B-aligned rows) reuses SH[0..16896).
__global__ __launch_bounds__(256) void gemm_qkv(
    const u16* __restrict__ A, const u16* __restrict__ Bt, const float* __restrict__ bias,
    u16* __restrict__ qO, u16* __restrict__ kO, u16* __restrict__ vO, int K) {
  constexpr int MI = 4, NJ = 4;
  __shared__ __align__(16) u16 SH[16896];   // 33792 B
  const int tid = threadIdx.x;
  const int lane = tid & 63, w = tid >> 6;  // 4 waves
  const int wr = w >> 1, wc = w & 1;
  const int lr = lane >> 4, lc = lane & 15;
  const long tileM = (long)blockIdx.y * 128;
  const long tileN = (long)blockIdx.x * 128;

  f32x4 acc[MI][NJ];
#pragma unroll
  for (int a = 0; a < MI; a++)
#pragma unroll
    for (int b = 0; b < NJ; b++) acc[a][b] = (f32x4){0.f, 0.f, 0.f, 0.f};

  const int r0 = lane >> 2;
  const int blk = lane & 3;

  auto stage = [&](int buf, int k0) {
#pragma unroll
    for (int i = 0; i < 2; i++) {
      int r = w * 32 + i * 16 + r0;
      int g = (blk ^ ((r >> 1) & 3)) << 3;
      async16(A + (tileM + r) * (long)K + k0 + g,
              (void*)&SH[buf * 4096 + (w * 32 + i * 16) * 32]);
      async16(Bt + (tileN + r) * (long)K + k0 + g,
              (void*)&SH[8192 + buf * 4096 + (w * 32 + i * 16) * 32]);
    }
  };

  stage(0, 0);
  for (int k0 = 0; k0 < K; k0 += 32) {
    const int cur = (k0 >> 5) & 1;
    stage(cur ^ 1, (k0 + 32 < K) ? k0 + 32 : 0);
    asm volatile("s_waitcnt vmcnt(4)" ::: "memory");
    asm volatile("s_barrier" ::: "memory");

    bf16x8 af[MI], bfv[NJ];
#pragma unroll
    for (int mi = 0; mi < MI; mi++) {
      int r = wr * 64 + mi * 16 + lc;
      af[mi] = *(const bf16x8*)&SH[cur * 4096 + r * 32 + ((lr ^ ((r >> 1) & 3)) << 3)];
    }
#pragma unroll
    for (int nj = 0; nj < NJ; nj++) {
      int r = wc * 64 + nj * 16 + lc;
      bfv[nj] = *(const bf16x8*)&SH[8192 + cur * 4096 + r * 32 + ((lr ^ ((r >> 1) & 3)) << 3)];
    }
#pragma unroll
    for (int mi = 0; mi < MI; mi++)
#pragma unroll
      for (int nj = 0; nj < NJ; nj++)
        acc[mi][nj] = __builtin_amdgcn_mfma_f32_16x16x32_bf16(af[mi], bfv[nj], acc[mi][nj], 0, 0, 0);
    asm volatile("s_barrier" ::: "memory");
  }

  // drain dummy prefetch DMAs before reusing SH as ET
  asm volatile("s_waitcnt vmcnt(0)" ::: "memory");
  __syncthreads();

  const int sec = (int)(tileN >> 9);           // 0 q, 1 k, 2 v (block-uniform)
  const int bb = (int)(tileM >> 12);           // batch
  const int t0b = (int)(tileM & 4095);
  const int h0 = ((int)(tileN & 511)) >> 6;    // first head of this block
  const float sc = (sec == 0) ? 0.18033688f : 1.f;   // q: 1/8 * log2(e)

  // write phase: ET[nloc][m] = f2bf((acc+bias)*sc), psi on m for V section
#pragma unroll
  for (int mi = 0; mi < MI; mi++)
#pragma unroll
    for (int nj = 0; nj < NJ; nj++) {
      int nloc = wc * 64 + nj * 16 + lc;
      float bcol = bias[tileN + nloc];
      int m0 = wr * 64 + mi * 16 + lr * 4;
      int p0 = m0;
      if (sec == 2) {  // psi: key-group g -> position-group ((g&3)<<1)|(g>>2)
        int gg = (m0 >> 2) & 7;
        int posg = ((gg & 3) << 1) | (gg >> 2);
        p0 = (m0 & ~31) | (posg << 2);
      }
      u16 tmp[4];
#pragma unroll
      for (int r = 0; r < 4; r++) tmp[r] = f2bf((acc[mi][nj][r] + bcol) * sc);
      *(uint2*)&SH[nloc * 132 + p0] = *(const uint2*)&tmp[0];
    }
  __syncthreads();

  // read/store phase: coalesced global writes
  if (sec == 2) {
    // V: [pl][d][pos]: ET row nloc -> h = h0+(nloc>>6), d = nloc&63
    const int rsub = tid >> 4;          // 0..15
    const int cch = tid & 15;           // 8-u16 chunk along pos
#pragma unroll
    for (int i = 0; i < 8; i++) {
      int row = i * 16 + rsub;
      int hh = row >> 6, d = row & 63;
      bf16x8 vv = *(const bf16x8*)&SH[row * 132 + cch * 8];
      long pl = bb * 8 + h0 + hh;
      *(bf16x8*)&vO[(pl * 64 + d) * 4096 + t0b + cch * 8] = vv;
    }
  } else {
    // q/k: [pl][t][d]: gather ET columns, store uint4 (wave writes 1KB contig)
    u16* dst = sec ? kO : qO;
    const int dgrp = lane & 7;          // d chunk of 8
    const int msub = lane >> 3;         // row within group
#pragma unroll
    for (int hh = 0; hh < 2; hh++) {
      long pl = bb * 8 + h0 + hh;
#pragma unroll
      for (int i = 0; i < 4; i++) {
        int m = w * 8 + msub + i * 32;
        u16 pk[8];
#pragma unroll
        for (int j = 0; j < 8; j++)
          pk[j] = SH[(hh * 64 + dgrp * 8 + j) * 132 + m];
        *(uint4*)&dst[((pl * 4096 + t0b + m) << 6) + dgrp * 8] = *(const uint4*)&pk[0];
      }
    }
  }
}

// ---------------- flash attention (R16 verbatim: split-K=2, in-reg P, 32 q/wave) ----------------
// Q,K bf16 [b*h,4096,64] (q pre-scaled by 0.125*log2e); VT bf16 [b*h,64,4096]
// psi-permuted along t within 32-key chunks.
// 8 waves x 32 q = 256 q/block; grid (16,16,2) = 512 blocks = 2/CU.
// LDS: KV dbuf 32KB only. In-register P: A-frag per chunk kk is the S^T
// C-layout (keys {4lr..4lr+3} from s[2kk], {16+4lr..16+4lr+3} from s[2kk+1]),
// compiler (__bf16) casts (R12-pinned). ones-MFMA l is perm-invariant.
__global__ __launch_bounds__(512, 4) void flash_attn(
    const u16* __restrict__ Q, const u16* __restrict__ Kg,
    const u16* __restrict__ VTg, u16* __restrict__ Op, float* __restrict__ lp) {
  __shared__ __align__(16) u16 KV[2][8192];   // per buf: Ks[64*64] | Vt[64*64]

  const int tid = threadIdx.x, lane = tid & 63, w = tid >> 6;  // w in 0..7
  // block-id relabel: all 16 qtiles of one (plane,split) -> same XCD (g%8)
  const int linear = blockIdx.x + 16 * (blockIdx.y + 16 * blockIdx.z);
  const int qt = linear >> 5;                  // qtile 0..15
  const int g = linear & 31;
  const int plane = g & 15;                    // b*8+h
  const int split = g >> 4;                    // 0/1: keys [0,2048) / [2048,4096)
  const int lr = lane >> 4, lc = lane & 15;
  const long pbase = (long)plane << 18;        // *4096*64
  const int qr0 = qt * 256 + w * 32;
  const int tj0 = split * 32;                  // first KV64 tile index

  bf16x8 bq[2][2];
#pragma unroll
  for (int qi = 0; qi < 2; qi++)
#pragma unroll
    for (int kk = 0; kk < 2; kk++)
      bq[qi][kk] = *(const bf16x8*)&Q[pbase + (long)(qr0 + qi * 16 + lc) * 64 + kk * 32 + lr * 8];

  bf16x8 ones;
#pragma unroll
  for (int u = 0; u < 8; u++) ones[u] = (__bf16)1.0f;
  const f32x4 zero4 = (f32x4){0.f, 0.f, 0.f, 0.f};

  f32x4 o[2][4], o1[2];
#pragma unroll
  for (int mi = 0; mi < 2; mi++) {
    o1[mi] = zero4;
#pragma unroll
    for (int nj = 0; nj < 4; nj++) o[mi][nj] = zero4;
  }

  const int krow = lane >> 3, kblk = lane & 7;   // 8 rows x 8 16B-blocks per inst

  auto stage = [&](int buf, int tj) {
    const u16* kS = Kg + pbase + (long)tj * 4096;
    const u16* vS = VTg + pbase + (long)tj * 64;
    int row = w * 8 + krow;
    async16(kS + (long)row * 64 + ((kblk ^ (row & 7)) << 3),
            (void*)&KV[buf][(w * 8) * 64]);
    async16(vS + (long)row * 4096 + ((kblk ^ (row & 7)) << 3),
            (void*)&KV[buf][4096 + (w * 8) * 64]);
  };

  stage(0, tj0);
  for (int j = 0; j < 32; j++) {
    const int cur = j & 1;
    stage(cur ^ 1, (j + 1 < 32) ? tj0 + j + 1 : tj0);  // j=31: dummy restage
    asm volatile("s_waitcnt vmcnt(2)" ::: "memory");
    asm volatile("s_barrier" ::: "memory");

    const u16* Ks = &KV[cur][0];
    const u16* Vt = &KV[cur][4096];

    // S^T tile: [64 key][32 q] per wave; zero4 C-in avoids per-iter zeroing
    f32x4 s[4][2];
#pragma unroll
    for (int ki = 0; ki < 4; ki++) {
      const int row = ki * 16 + lc;
      bf16x8 ak[2];
#pragma unroll
      for (int kk = 0; kk < 2; kk++)
        ak[kk] = *(const bf16x8*)&Ks[row * 64 + (((kk * 4 + lr) ^ (row & 7)) << 3)];
#pragma unroll
      for (int qi = 0; qi < 2; qi++) {
        s[ki][qi] = __builtin_amdgcn_mfma_f32_16x16x32_bf16(ak[0], bq[qi][0], zero4, 0, 0, 0);
        s[ki][qi] = __builtin_amdgcn_mfma_f32_16x16x32_bf16(ak[1], bq[qi][1], s[ki][qi], 0, 0, 0);
      }
    }

    // p = exp2(s) -> bf16 (compiler casts); A-frag IS the C-layout
    // (V is psi-permuted), zero cross-lane ops, no LDS.
#pragma unroll
    for (int kk = 0; kk < 2; kk++) {
      bf16x8 ap[2];
#pragma unroll
      for (int qi = 0; qi < 2; qi++) {
        bf16x8 p;
#pragma unroll
        for (int r = 0; r < 4; r++) {
          p[r]     = (__bf16)__builtin_amdgcn_exp2f(s[2 * kk][qi][r]);
          p[4 + r] = (__bf16)__builtin_amdgcn_exp2f(s[2 * kk + 1][qi][r]);
        }
        ap[qi] = p;
      }
#pragma unroll
      for (int nj = 0; nj < 4; nj++) {
        const int row = nj * 16 + lc;
        bf16x8 bv = *(const bf16x8*)&Vt[row * 64 + (((kk * 4 + lr) ^ (row & 7)) << 3)];
#pragma unroll
        for (int mi = 0; mi < 2; mi++)
          o[mi][nj] = __builtin_amdgcn_mfma_f32_16x16x32_bf16(ap[mi], bv, o[mi][nj], 0, 0, 0);
      }
#pragma unroll
      for (int mi = 0; mi < 2; mi++)
        o1[mi] = __builtin_amdgcn_mfma_f32_16x16x32_bf16(ap[mi], ones, o1[mi], 0, 0, 0);
    }
    asm volatile("s_barrier" ::: "memory");
  }

  // epilogue: bf16 O-partial (undivided) + fp32 l-partial
  const int bb = plane >> 3, h = plane & 7;
  u16* Ob = Op + (long)split * 4194304;        // 8 MiB per split
#pragma unroll
  for (int mi = 0; mi < 2; mi++)
#pragma unroll
    for (int r = 0; r < 4; r++) {
      long t = qr0 + mi * 16 + 4 * lr + r;
#pragma unroll
      for (int nj = 0; nj < 4; nj++)
        Ob[(((long)(bb * 4096 + t) * 8 + h) << 6) + nj * 16 + lc] = f2bf(o[mi][nj][r]);
      if (lc == 0) lp[((split * 16 + plane) << 12) + t] = o1[mi][r];
    }
}

// ---------------- out GEMM (+fused split-K merge): out = ((O0+O1)/l) @ woT^T + bo ----------------
// A staged through VGPRs: (O0+O1)*inv(l0+l1) -> bf16 -> LDS. B via async16 DMA.
__global__ __launch_bounds__(256) void gemm_out(
    const u16* __restrict__ Op, const float* __restrict__ lp,
    const u16* __restrict__ Bt, const float* __restrict__ bias,
    float* __restrict__ outf) {
  constexpr int K = 512;
  __shared__ __align__(16) u16 As[2][64 * 32];
  __shared__ __align__(16) u16 Bs[2][64 * 32];
  const int tid = threadIdx.x;
  const int lane = tid & 63, w = tid >> 6;
  const int wr = w >> 1, wc = w & 1;
  const int lr = lane >> 4, lc = lane & 15;
  const long tileM = (long)blockIdx.y * 64;
  const long tileN = (long)blockIdx.x * 64;

  f32x4 acc[2][2];
#pragma unroll
  for (int a = 0; a < 2; a++)
#pragma unroll
    for (int b = 0; b < 2; b++) acc[a][b] = (f32x4){0.f, 0.f, 0.f, 0.f};

  const int r0 = lane >> 2;
  const int blk = lane & 3;

  auto stageB = [&](int buf, int k0) {
    int r = w * 16 + r0;
    int g = (blk ^ ((r >> 1) & 3)) << 3;
    async16(Bt + (tileN + r) * (long)K + k0 + g, (void*)&Bs[buf][(w * 16) * 32]);
  };

  // A merge-staging geometry: thread covers row ar, 16B block ablk
  const int ar = tid >> 2, ablk = tid & 3;
  const long arow = tileM + ar;
  const int ab = (int)(arow >> 12), at = (int)(arow & 4095);

  auto stageA = [&](int buf, int k0) {
    int h = k0 >> 6;
    float l = lp[(long)((ab * 8 + h) << 12) + at] +
              lp[(long)((16 + ab * 8 + h) << 12) + at];
    float inv = 1.f / l;
    long idx = arow * 512 + k0 + ablk * 8;
    bf16x8 v0 = *(const bf16x8*)&Op[idx];
    bf16x8 v1 = *(const bf16x8*)&Op[4194304 + idx];
    u16 tmp[8];
#pragma unroll
    for (int e = 0; e < 8; e++)
      tmp[e] = f2bf(((float)v0[e] + (float)v1[e]) * inv);
    *(uint4*)&As[buf][ar * 32 + ((ablk ^ ((ar >> 1) & 3)) << 3)] = *(const uint4*)&tmp[0];
  };

  stageB(0, 0);
  for (int k0 = 0; k0 < K; k0 += 32) {
    const int cur = (k0 >> 5) & 1;
    stageB(cur ^ 1, (k0 + 32 < K) ? k0 + 32 : 0);
    stageA(cur, k0);
    // drain A ds_writes + this tile's B DMA; leave next-B (1 inst) in flight
    asm volatile("s_waitcnt vmcnt(1) lgkmcnt(0)" ::: "memory");
    asm volatile("s_barrier" ::: "memory");

    bf16x8 af[2], bfv[2];
#pragma unroll
    for (int mi = 0; mi < 2; mi++) {
      int r = wr * 32 + mi * 16 + lc;
      af[mi] = *(const bf16x8*)&As[cur][r * 32 + ((lr ^ ((r >> 1) & 3)) << 3)];
    }
#pragma unroll
    for (int nj = 0; nj < 2; nj++) {
      int r = wc * 32 + nj * 16 + lc;
      bfv[nj] = *(const bf16x8*)&Bs[cur][r * 32 + ((lr ^ ((r >> 1) & 3)) << 3)];
    }
#pragma unroll
    for (int mi = 0; mi < 2; mi++)
#pragma unroll
      for (int nj = 0; nj < 2; nj++)
        acc[mi][nj] = __builtin_amdgcn_mfma_f32_16x16x32_bf16(af[mi], bfv[nj], acc[mi][nj], 0, 0, 0);
    asm volatile("s_barrier" ::: "memory");
  }

#pragma unroll
  for (int mi = 0; mi < 2; mi++)
#pragma unroll
    for (int nj = 0; nj < 2; nj++) {
      long col = tileN + wc * 32 + nj * 16 + lc;
      float bcol = bias[col];
      long row0 = tileM + wr * 32 + mi * 16 + lr * 4;
#pragma unroll
      for (int r = 0; r < 4; r++)
        outf[(row0 + r) * 256 + col] = acc[mi][nj][r] + bcol;
    }
}

// ---------------- launch ----------------
extern "C" void kernel_launch(void* const* d_in, const int* in_sizes, int n_in,
                              void* d_out, int out_size, void* d_ws, size_t ws_size,
                              hipStream_t stream) {
  const float* prompt = (const float*)d_in[0];
  const float* Wp = (const float*)d_in[1];
  const float* bp = (const float*)d_in[2];
  const float* Wqkv = (const float*)d_in[3];
  const float* bqkv = (const float*)d_in[4];
  const float* Wo = (const float*)d_in[5];
  const float* bo = (const float*)d_in[6];
  float* out = (float*)d_out;

  char* ws = (char*)d_ws;
  const size_t MiB = 1024 * 1024;
  u16* qb     = (u16*)(ws + 0);           // [b,h,t,d]  8 MiB
  u16* kb     = (u16*)(ws + 8 * MiB);     // [b,h,t,d]  8 MiB
  u16* vb     = (u16*)(ws + 16 * MiB);    // [b,h,d,t(psi)]  8 MiB (transposed)
  u16* pbf    = (u16*)(ws + 24 * MiB);    // [8192,256] bf16 4 MiB (dead after qkv)
  float* lpp  = (float*)(ws + 24 * MiB);  // [2][16][4096] fp32 512 KiB (overlays pbf)
  u16* Op     = (u16*)(ws + 28 * MiB);    // [2][b,t,h*d] bf16 partials, 2x8 MiB
  u16* woT    = (u16*)(ws + 44 * MiB);                  // [256,512]  256 KiB
  u16* wfT    = (u16*)(ws + 44 * MiB + 256 * 1024);     // [1536,256] 768 KiB
  float* bfused = (float*)(ws + 45 * MiB);              // [1536] fp32

  prep_kernel<<<dim3(2680), dim3(256), 0, stream>>>(
      prompt, pbf, Wp, Wqkv, Wo, woT, bp, bqkv, bfused, wfT);

  // qkv = prompt @ Wfused + bfused -> q(scaled)/k [b,h,t,d], v^T [b,h,d,t(psi)]
  gemm_qkv<<<dim3(12, 64), dim3(256), 0, stream>>>(
      pbf, wfT, bfused, qb, kb, vb, 256);

  // flash attention: in-register P, 256 q/block, 512 blocks = 2/CU
  flash_attn<<<dim3(16, 16, 2), dim3(512), 0, stream>>>(qb, kb, vb, Op, lpp);

  // out = ((O0+O1)/(l0+l1)) @ Wo + bo  (merge fused into A-staging)
  gemm_out<<<dim3(4, 128), dim3(256), 0, stream>>>(Op, lpp, woT, bo, out);
}